// Round 7
// baseline (337.668 us; speedup 1.0000x reference)
//
#include <hip/hip_runtime.h>

constexpr int NB = 2;
constexpr int NC = 64;
constexpr int NH = 192;
constexpr int NW = 192;
constexpr int NK = 7;
constexpr int NHW = NH * NW;          // 36864
constexpr int NPIX = NB * NHW;        // 73728
constexpr float EPS = 1e-6f;

// ---------------------------------------------------------------------------
// Kernel 1 (v7): layernorm + 1x1 conv, pure-register formulation.
// Block = 64 pixels x 4 waves. Each wave computes 32 of the 128 outputs
// (kind = q/k, half = lo/hi 32) for the same 64 px; layernorm recomputed
// per wave (L1-shared g lines). z[64] in VGPRs, weights via uniform s_load.
// ---------------------------------------------------------------------------
__global__ __launch_bounds__(256, 4) void qk_reg(
    const float* __restrict__ g, const float* __restrict__ cd,
    const float* __restrict__ mask,
    const float* __restrict__ ln_w, const float* __restrict__ ln_b,
    const float* __restrict__ conv_w, const float* __restrict__ conv_b,
    float* __restrict__ qbuf, float* __restrict__ kbuf)
{
    int tid  = threadIdx.x;
    int lane = tid & 63;
    int wv   = __builtin_amdgcn_readfirstlane(tid >> 6);
    int kind = wv >> 1;                 // 0 -> q rows, 1 -> k rows
    int half = wv & 1;                  // lo/hi 32 outputs

    int b  = blockIdx.x / (NHW / 64);   // 576 blocks per batch
    int hw = (blockIdx.x - b * (NHW / 64)) * 64 + lane;
    int p  = b * NHW + hw;

    const float* gp = g + (size_t)b * NC * NHW + hw;

    float z[NC];
    float s0 = 0.f, s1 = 0.f, t0 = 0.f, t1 = 0.f;
#pragma unroll
    for (int c = 0; c < NC; c += 2) {
        float v0 = gp[(size_t)c * NHW];
        float v1 = gp[(size_t)(c + 1) * NHW];
        z[c] = v0; z[c + 1] = v1;
        s0 += v0; s1 += v1;
        t0 = fmaf(v0, v0, t0); t1 = fmaf(v1, v1, t1);
    }
    float mu   = (s0 + s1) * (1.f / NC);
    float var  = (t0 + t1) * (1.f / NC) - mu * mu;
    float rstd = rsqrtf(var + EPS);
#pragma unroll
    for (int c = 0; c < NC; c += 4) {
        float4 lw = *(const float4*)&ln_w[c];
        float4 lb = *(const float4*)&ln_b[c];
        z[c]     = fmaf((z[c]     - mu) * rstd, lw.x, lb.x);
        z[c + 1] = fmaf((z[c + 1] - mu) * rstd, lw.y, lb.y);
        z[c + 2] = fmaf((z[c + 2] - mu) * rstd, lw.z, lb.z);
        z[c + 3] = fmaf((z[c + 3] - mu) * rstd, lw.w, lb.w);
    }
    float zcd  = cd[p];
    float mval = mask[p];

    int orow = kind * 64 + half * 32;   // conv_w row base (wave-uniform)
    float* outb = (kind ? kbuf : qbuf) + ((size_t)b * NC + half * 32) * NHW + hw;

    for (int oo = 0; oo < 32; oo += 2) {
        const float* wr0 = conv_w + (size_t)(orow + oo) * 65;  // uniform
        const float* wr1 = wr0 + 65;
        float a0 = conv_b[orow + oo];
        float a1 = conv_b[orow + oo + 1];
#pragma unroll
        for (int c = 0; c < NC; ++c) {
            a0 = fmaf(wr0[c], z[c], a0);
            a1 = fmaf(wr1[c], z[c], a1);
        }
        a0 = fmaf(wr0[NC], zcd, a0);
        a1 = fmaf(wr1[NC], zcd, a1);
        if (kind) { a0 *= mval; a1 *= mval; }
        outb[(size_t)oo * NHW]       = a0;
        outb[(size_t)(oo + 1) * NHW] = a1;
    }
}

// ---------------------------------------------------------------------------
// Kernel 2 (v7): DPP attention, channel-split x2, edge columns in extra blocks.
// Interior (blk < 768): block = 2 rows x 48-px strip; wave = (row, chhalf).
//   Channel loop barrier-free; one LDS exchange combines the two halves.
//   Only pixels with unclamped column windows (w in [3,188]) are stored.
// Edge (blk >= 768): wave per (b,h); lane = window position; both image-edge
//   column groups (w<3 share window cs=0; w>188 share cs=185) via shfl-reduce.
// DPP facts (verified R6): 0x130 => lane i <- i+1; 0x138 => lane i <- i-1.
// ---------------------------------------------------------------------------
__device__ inline float dpp_p1(float x) {
    return __int_as_float(__builtin_amdgcn_mov_dpp(
        __float_as_int(x), 0x130, 0xf, 0xf, true));
}
__device__ inline float dpp_m1(float x) {
    return __int_as_float(__builtin_amdgcn_mov_dpp(
        __float_as_int(x), 0x138, 0xf, 0xf, true));
}
__device__ inline float wred_max(float v) {
#pragma unroll
    for (int m = 1; m < 64; m <<= 1) v = fmaxf(v, __shfl_xor(v, m));
    return v;
}
__device__ inline float wred_sum(float v) {
#pragma unroll
    for (int m = 1; m < 64; m <<= 1) v += __shfl_xor(v, m);
    return v;
}

__global__ __launch_bounds__(256, 4) void attn_fused(
    const float* __restrict__ qbuf, const float* __restrict__ kbuf,
    const float* __restrict__ cd, const float* __restrict__ sd,
    const float* __restrict__ mask, const float* __restrict__ rpb,
    float* __restrict__ out_cd, float* __restrict__ out_mask)
{
    __shared__ float xch[2][48][49];    // 18.8 KB logit exchange

    int tid  = threadIdx.x;
    int lane = tid & 63;
    int wv   = __builtin_amdgcn_readfirstlane(tid >> 6);
    int blk  = blockIdx.x;

    if (blk < 768) {
        // ------------------ interior path ------------------
        int b   = blk / 384;
        int r   = blk % 384;
        int s   = r / 96;
        int h0  = (r % 96) * 2;
        int pair = wv >> 1;
        int chh  = wv & 1;
        int h  = h0 + pair;
        int wp = s * 48 + lane - 8;
        int wc = min(max(wp, 0), NW - 1);
        int rs = min(max(h - 3, 0), NH - NK);

        const float* kb = kbuf + (size_t)(b * NC + chh * 32) * NHW + rs * NW + wc;
        const float* qb = qbuf + (size_t)(b * NC + chh * 32) * NHW + h * NW + wc;

        float at[49];
#pragma unroll
        for (int n = 0; n < 49; ++n) at[n] = 0.f;

        float kvA[7], kvB[7];
        auto loadrow = [&](float (&dst)[7], int c) {
            const float* pp = kb + (size_t)c * NHW;
#pragma unroll
            for (int rr = 0; rr < 7; ++rr) dst[rr] = pp[rr * NW];
        };
        auto compute = [&](float (&cur)[7], float qc) {
#pragma unroll
            for (int rr = 0; rr < 7; ++rr) {
                float c0 = cur[rr];
                float p1 = dpp_p1(c0), p2 = dpp_p1(p1), p3 = dpp_p1(p2);
                float m1 = dpp_m1(c0), m2 = dpp_m1(m1), m3 = dpp_m1(m2);
                at[rr*7+0] = fmaf(qc, m3, at[rr*7+0]);
                at[rr*7+1] = fmaf(qc, m2, at[rr*7+1]);
                at[rr*7+2] = fmaf(qc, m1, at[rr*7+2]);
                at[rr*7+3] = fmaf(qc, c0, at[rr*7+3]);
                at[rr*7+4] = fmaf(qc, p1, at[rr*7+4]);
                at[rr*7+5] = fmaf(qc, p2, at[rr*7+5]);
                at[rr*7+6] = fmaf(qc, p3, at[rr*7+6]);
            }
        };

        float q0 = qb[0], q1 = qb[(size_t)1 * NHW];
        loadrow(kvA, 0);
        for (int c = 0; c < 32; c += 2) {
            if (c + 1 < 32) loadrow(kvB, c + 1);
            compute(kvA, q0);
            if (c + 2 < 32) { q0 = qb[(size_t)(c + 2) * NHW]; loadrow(kvA, c + 2); }
            if (c + 1 < 32) compute(kvB, q1);
            if (c + 3 < 32) q1 = qb[(size_t)(c + 3) * NHW];
        }

        bool act = (lane >= 8 && lane < 56);
        int px = lane - 8;
        if (chh == 1 && act) {
#pragma unroll
            for (int n = 0; n < 49; ++n) xch[pair][px][n] = at[n];
        }
        __syncthreads();
        if (chh == 0) {
            if (act) {
#pragma unroll
                for (int n = 0; n < 49; ++n) at[n] += xch[pair][px][n];
            }
            // bias (stored px all have pc == 3; pr wave-uniform)
            int pr = 6 - (h - rs);
            const float* rp = rpb + pr * 13 + 3;
#pragma unroll
            for (int i = 0; i < 7; ++i)
#pragma unroll
                for (int j = 0; j < 7; ++j)
                    at[i*7+j] += rp[i * 13 + j];

            float mx = -1e30f;
#pragma unroll
            for (int n = 0; n < 49; ++n) mx = fmaxf(mx, at[n]);
            float sm = 0.f;
#pragma unroll
            for (int n = 0; n < 49; ++n) { at[n] = __expf(at[n] - mx); sm += at[n]; }
            float inv = 1.f / sm;

            const float* cdb = cd   + (size_t)b * NHW;
            const float* msb = mask + (size_t)b * NHW;
            float oc = 0.f, om = 0.f, cdc = 0.f, mc = 0.f;
            int hr = h - rs;   // wave-uniform
#pragma unroll
            for (int rr = 0; rr < 7; ++rr) {
                float c0 = cdb[(rs + rr) * NW + wc];
                float m0 = msb[(rs + rr) * NW + wc];
                if (rr == hr) { cdc = c0; mc = m0; }
                float cp1 = dpp_p1(c0), cp2 = dpp_p1(cp1), cp3 = dpp_p1(cp2);
                float cm1 = dpp_m1(c0), cm2 = dpp_m1(cm1), cm3 = dpp_m1(cm2);
                float mp1 = dpp_p1(m0), mp2 = dpp_p1(mp1), mp3 = dpp_p1(mp2);
                float mm1 = dpp_m1(m0), mm2 = dpp_m1(mm1), mm3 = dpp_m1(mm2);
                oc = fmaf(at[rr*7+0], cm3, oc); om = fmaf(at[rr*7+0], mm3, om);
                oc = fmaf(at[rr*7+1], cm2, oc); om = fmaf(at[rr*7+1], mm2, om);
                oc = fmaf(at[rr*7+2], cm1, oc); om = fmaf(at[rr*7+2], mm1, om);
                oc = fmaf(at[rr*7+3], c0 , oc); om = fmaf(at[rr*7+3], m0 , om);
                oc = fmaf(at[rr*7+4], cp1, oc); om = fmaf(at[rr*7+4], mp1, om);
                oc = fmaf(at[rr*7+5], cp2, oc); om = fmaf(at[rr*7+5], mp2, om);
                oc = fmaf(at[rr*7+6], cp3, oc); om = fmaf(at[rr*7+6], mp3, om);
            }
            oc *= inv; om *= inv;

            float sdc = sd[(size_t)b * NHW + h * NW + wc];
            float co = oc * mc + cdc * (1.f - mc);
            float mo = om;
            if (sdc > 0.f) { co = sdc; mo = mc; }
            if (act && wp >= 3 && wp <= 188) {
                int pidx = b * NHW + h * NW + wp;
                out_cd[pidx] = co;
                out_mask[pidx] = mo;
            }
        }
    } else {
        // ------------------ edge-column path ------------------
        int id = (blk - 768) * 4 + wv;     // 0..383
        int b  = id / 192;
        int h  = id % 192;
        int rs = min(max(h - 3, 0), NH - NK);
        int pr = 6 - (h - rs);
        int l  = lane;
        int i  = l / 7, j = l % 7;
        int ic = min(i, 6);
        bool al = (l < 49);

        const float* kb = kbuf + (size_t)b * NC * NHW;
        const float* qb = qbuf + (size_t)b * NC * NHW + h * NW;
        int offL = (rs + ic) * NW + j;          // left window: cs = 0
        int offR = (rs + ic) * NW + 185 + j;    // right window: cs = 185

        float aL0 = 0.f, aL1 = 0.f, aL2 = 0.f;
        float aR0 = 0.f, aR1 = 0.f, aR2 = 0.f;
        for (int c = 0; c < NC; ++c) {
            const float* kc = kb + (size_t)c * NHW;
            const float* qc = qb + (size_t)c * NHW;
            float kl = kc[offL], kr = kc[offR];
            float ql0 = qc[0],   ql1 = qc[1],   ql2 = qc[2];
            float qr0 = qc[189], qr1 = qc[190], qr2 = qc[191];
            aL0 = fmaf(ql0, kl, aL0); aL1 = fmaf(ql1, kl, aL1);
            aL2 = fmaf(ql2, kl, aL2);
            aR0 = fmaf(qr0, kr, aR0); aR1 = fmaf(qr1, kr, aR1);
            aR2 = fmaf(qr2, kr, aR2);
        }
        // bias: pc = 6,5,4 (left px 0,1,2), pc = 2,1,0 (right px 189,190,191)
        const float* rp = rpb + (pr + ic) * 13 + j;
        aL0 += rp[6]; aL1 += rp[5]; aL2 += rp[4];
        aR0 += rp[2]; aR1 += rp[1]; aR2 += rp[0];

        float e0, e1, e2, e3, e4, e5, s0, s1, s2, s3, s4, s5;
        {
            float v;
            v = al ? aL0 : -1e30f; v = wred_max(v);
            e0 = al ? __expf(aL0 - v) : 0.f; s0 = wred_sum(e0);
            v = al ? aL1 : -1e30f; v = wred_max(v);
            e1 = al ? __expf(aL1 - v) : 0.f; s1 = wred_sum(e1);
            v = al ? aL2 : -1e30f; v = wred_max(v);
            e2 = al ? __expf(aL2 - v) : 0.f; s2 = wred_sum(e2);
            v = al ? aR0 : -1e30f; v = wred_max(v);
            e3 = al ? __expf(aR0 - v) : 0.f; s3 = wred_sum(e3);
            v = al ? aR1 : -1e30f; v = wred_max(v);
            e4 = al ? __expf(aR1 - v) : 0.f; s4 = wred_sum(e4);
            v = al ? aR2 : -1e30f; v = wred_max(v);
            e5 = al ? __expf(aR2 - v) : 0.f; s5 = wred_sum(e5);
        }

        const float* cdb = cd   + (size_t)b * NHW;
        const float* msb = mask + (size_t)b * NHW;
        float cdL = cdb[offL], mL = msb[offL];
        float cdR = cdb[offR], mR = msb[offR];

        float oc0 = wred_sum(e0 * cdL), om0 = wred_sum(e0 * mL);
        float oc1 = wred_sum(e1 * cdL), om1 = wred_sum(e1 * mL);
        float oc2 = wred_sum(e2 * cdL), om2 = wred_sum(e2 * mL);
        float oc3 = wred_sum(e3 * cdR), om3 = wred_sum(e3 * mR);
        float oc4 = wred_sum(e4 * cdR), om4 = wred_sum(e4 * mR);
        float oc5 = wred_sum(e5 * cdR), om5 = wred_sum(e5 * mR);

        if (lane < 6) {
            int wpx = (lane < 3) ? lane : (186 + lane);
            float ocv = lane==0?oc0 : lane==1?oc1 : lane==2?oc2
                      : lane==3?oc3 : lane==4?oc4 : oc5;
            float omv = lane==0?om0 : lane==1?om1 : lane==2?om2
                      : lane==3?om3 : lane==4?om4 : om5;
            float smv = lane==0?s0  : lane==1?s1  : lane==2?s2
                      : lane==3?s3  : lane==4?s4  : s5;
            float inv = 1.f / smv;
            float oc = ocv * inv, om = omv * inv;
            int pidx = b * NHW + h * NW + wpx;
            float cdc = cdb[h * NW + wpx];
            float mc  = msb[h * NW + wpx];
            float sdc = sd[pidx];
            float co = oc * mc + cdc * (1.f - mc);
            float mo = om;
            if (sdc > 0.f) { co = sdc; mo = mc; }
            out_cd[pidx] = co;
            out_mask[pidx] = mo;
        }
    }
}

extern "C" void kernel_launch(void* const* d_in, const int* in_sizes, int n_in,
                              void* d_out, int out_size, void* d_ws, size_t ws_size,
                              hipStream_t stream) {
    const float* g      = (const float*)d_in[0];
    const float* cd     = (const float*)d_in[1];
    const float* sd     = (const float*)d_in[2];
    const float* mask   = (const float*)d_in[3];
    const float* ln_w   = (const float*)d_in[4];
    const float* ln_b   = (const float*)d_in[5];
    const float* conv_w = (const float*)d_in[6];
    const float* conv_b = (const float*)d_in[7];
    const float* rpb    = (const float*)d_in[8];

    float* out  = (float*)d_out;                 // [cd_out | mask_out]
    float* qbuf = (float*)d_ws;                  // NB*NC*NHW floats
    float* kbuf = qbuf + (size_t)NB * NC * NHW;  // NB*NC*NHW floats

    qk_reg<<<dim3(NPIX / 64), dim3(256), 0, stream>>>(
        g, cd, mask, ln_w, ln_b, conv_w, conv_b, qbuf, kbuf);
    attn_fused<<<dim3(768 + 96), dim3(256), 0, stream>>>(
        qbuf, kbuf, cd, sd, mask, rpb, out, out + NPIX);
}

// Round 8
// 162.820 us; speedup vs baseline: 2.0739x; 2.0739x over previous
//
#include <hip/hip_runtime.h>

constexpr int NB = 2;
constexpr int NC = 64;
constexpr int NH = 192;
constexpr int NW = 192;
constexpr int NK = 7;
constexpr int NHW = NH * NW;          // 36864
constexpr int NPIX = NB * NHW;        // 73728
constexpr float EPS = 1e-6f;

// ---------------------------------------------------------------------------
// Kernel 1 (v8): layernorm + 1x1 conv, pure-register formulation.
// NOTE: plain __launch_bounds__(256). R7's (256,4) clamped VGPRs to 64 and
// spilled z[64] to scratch (WRITE_SIZE 197 MB, VALUBusy 0.3%). Never add a
// min-waves hint to a kernel whose register working set is near 100.
// ---------------------------------------------------------------------------
__global__ __launch_bounds__(256) void qk_reg(
    const float* __restrict__ g, const float* __restrict__ cd,
    const float* __restrict__ mask,
    const float* __restrict__ ln_w, const float* __restrict__ ln_b,
    const float* __restrict__ conv_w, const float* __restrict__ conv_b,
    float* __restrict__ qbuf, float* __restrict__ kbuf)
{
    int tid  = threadIdx.x;
    int lane = tid & 63;
    int wv   = __builtin_amdgcn_readfirstlane(tid >> 6);
    int kind = wv >> 1;                 // 0 -> q rows, 1 -> k rows
    int half = wv & 1;                  // lo/hi 32 outputs

    int b  = blockIdx.x / (NHW / 64);   // 576 blocks per batch
    int hw = (blockIdx.x - b * (NHW / 64)) * 64 + lane;
    int p  = b * NHW + hw;

    const float* gp = g + (size_t)b * NC * NHW + hw;

    float z[NC];
    float s0 = 0.f, s1 = 0.f, t0 = 0.f, t1 = 0.f;
#pragma unroll
    for (int c = 0; c < NC; c += 2) {
        float v0 = gp[(size_t)c * NHW];
        float v1 = gp[(size_t)(c + 1) * NHW];
        z[c] = v0; z[c + 1] = v1;
        s0 += v0; s1 += v1;
        t0 = fmaf(v0, v0, t0); t1 = fmaf(v1, v1, t1);
    }
    float mu   = (s0 + s1) * (1.f / NC);
    float var  = (t0 + t1) * (1.f / NC) - mu * mu;
    float rstd = rsqrtf(var + EPS);
#pragma unroll
    for (int c = 0; c < NC; c += 4) {
        float4 lw = *(const float4*)&ln_w[c];
        float4 lb = *(const float4*)&ln_b[c];
        z[c]     = fmaf((z[c]     - mu) * rstd, lw.x, lb.x);
        z[c + 1] = fmaf((z[c + 1] - mu) * rstd, lw.y, lb.y);
        z[c + 2] = fmaf((z[c + 2] - mu) * rstd, lw.z, lb.z);
        z[c + 3] = fmaf((z[c + 3] - mu) * rstd, lw.w, lb.w);
    }
    float zcd  = cd[p];
    float mval = mask[p];

    int orow = kind * 64 + half * 32;   // conv_w row base (wave-uniform)
    float* outb = (kind ? kbuf : qbuf) + ((size_t)b * NC + half * 32) * NHW + hw;

    for (int oo = 0; oo < 32; oo += 2) {
        const float* wr0 = conv_w + (size_t)(orow + oo) * 65;  // uniform
        const float* wr1 = wr0 + 65;
        float a0 = conv_b[orow + oo];
        float a1 = conv_b[orow + oo + 1];
#pragma unroll
        for (int c = 0; c < NC; ++c) {
            a0 = fmaf(wr0[c], z[c], a0);
            a1 = fmaf(wr1[c], z[c], a1);
        }
        a0 = fmaf(wr0[NC], zcd, a0);
        a1 = fmaf(wr1[NC], zcd, a1);
        if (kind) { a0 *= mval; a1 *= mval; }
        outb[(size_t)oo * NHW]       = a0;
        outb[(size_t)(oo + 1) * NHW] = a1;
    }
}

// ---------------------------------------------------------------------------
// Kernel 2 (v8): DPP attention, channel-split x2, edge columns in extra
// blocks. Same structure as R7 but plain __launch_bounds__(256) (no VGPR
// clamp -> no spill).
// DPP facts (verified R6): 0x130 => lane i <- i+1; 0x138 => lane i <- i-1.
// ---------------------------------------------------------------------------
__device__ inline float dpp_p1(float x) {
    return __int_as_float(__builtin_amdgcn_mov_dpp(
        __float_as_int(x), 0x130, 0xf, 0xf, true));
}
__device__ inline float dpp_m1(float x) {
    return __int_as_float(__builtin_amdgcn_mov_dpp(
        __float_as_int(x), 0x138, 0xf, 0xf, true));
}
__device__ inline float wred_max(float v) {
#pragma unroll
    for (int m = 1; m < 64; m <<= 1) v = fmaxf(v, __shfl_xor(v, m));
    return v;
}
__device__ inline float wred_sum(float v) {
#pragma unroll
    for (int m = 1; m < 64; m <<= 1) v += __shfl_xor(v, m);
    return v;
}

__global__ __launch_bounds__(256) void attn_fused(
    const float* __restrict__ qbuf, const float* __restrict__ kbuf,
    const float* __restrict__ cd, const float* __restrict__ sd,
    const float* __restrict__ mask, const float* __restrict__ rpb,
    float* __restrict__ out_cd, float* __restrict__ out_mask)
{
    __shared__ float xch[2][48][49];    // 18.8 KB logit exchange

    int tid  = threadIdx.x;
    int lane = tid & 63;
    int wv   = __builtin_amdgcn_readfirstlane(tid >> 6);
    int blk  = blockIdx.x;

    if (blk < 768) {
        // ------------------ interior path ------------------
        int b   = blk / 384;
        int r   = blk % 384;
        int s   = r / 96;
        int h0  = (r % 96) * 2;
        int pair = wv >> 1;
        int chh  = wv & 1;
        int h  = h0 + pair;
        int wp = s * 48 + lane - 8;
        int wc = min(max(wp, 0), NW - 1);
        int rs = min(max(h - 3, 0), NH - NK);

        const float* kb = kbuf + (size_t)(b * NC + chh * 32) * NHW + rs * NW + wc;
        const float* qb = qbuf + (size_t)(b * NC + chh * 32) * NHW + h * NW + wc;

        float at[49];
#pragma unroll
        for (int n = 0; n < 49; ++n) at[n] = 0.f;

        float kvA[7], kvB[7];
        auto loadrow = [&](float (&dst)[7], int c) {
            const float* pp = kb + (size_t)c * NHW;
#pragma unroll
            for (int rr = 0; rr < 7; ++rr) dst[rr] = pp[rr * NW];
        };
        auto compute = [&](float (&cur)[7], float qc) {
#pragma unroll
            for (int rr = 0; rr < 7; ++rr) {
                float c0 = cur[rr];
                float p1 = dpp_p1(c0), p2 = dpp_p1(p1), p3 = dpp_p1(p2);
                float m1 = dpp_m1(c0), m2 = dpp_m1(m1), m3 = dpp_m1(m2);
                at[rr*7+0] = fmaf(qc, m3, at[rr*7+0]);
                at[rr*7+1] = fmaf(qc, m2, at[rr*7+1]);
                at[rr*7+2] = fmaf(qc, m1, at[rr*7+2]);
                at[rr*7+3] = fmaf(qc, c0, at[rr*7+3]);
                at[rr*7+4] = fmaf(qc, p1, at[rr*7+4]);
                at[rr*7+5] = fmaf(qc, p2, at[rr*7+5]);
                at[rr*7+6] = fmaf(qc, p3, at[rr*7+6]);
            }
        };

        float q0 = qb[0], q1 = qb[(size_t)1 * NHW];
        loadrow(kvA, 0);
        for (int c = 0; c < 32; c += 2) {
            if (c + 1 < 32) loadrow(kvB, c + 1);
            compute(kvA, q0);
            if (c + 2 < 32) { q0 = qb[(size_t)(c + 2) * NHW]; loadrow(kvA, c + 2); }
            if (c + 1 < 32) compute(kvB, q1);
            if (c + 3 < 32) q1 = qb[(size_t)(c + 3) * NHW];
        }

        bool act = (lane >= 8 && lane < 56);
        int px = lane - 8;
        if (chh == 1 && act) {
#pragma unroll
            for (int n = 0; n < 49; ++n) xch[pair][px][n] = at[n];
        }
        __syncthreads();
        if (chh == 0) {
            if (act) {
#pragma unroll
                for (int n = 0; n < 49; ++n) at[n] += xch[pair][px][n];
            }
            // bias (stored px all have pc == 3; pr wave-uniform)
            int pr = 6 - (h - rs);
            const float* rp = rpb + pr * 13 + 3;
#pragma unroll
            for (int i = 0; i < 7; ++i)
#pragma unroll
                for (int j = 0; j < 7; ++j)
                    at[i*7+j] += rp[i * 13 + j];

            float mx = -1e30f;
#pragma unroll
            for (int n = 0; n < 49; ++n) mx = fmaxf(mx, at[n]);
            float sm = 0.f;
#pragma unroll
            for (int n = 0; n < 49; ++n) { at[n] = __expf(at[n] - mx); sm += at[n]; }
            float inv = 1.f / sm;

            const float* cdb = cd   + (size_t)b * NHW;
            const float* msb = mask + (size_t)b * NHW;
            float oc = 0.f, om = 0.f, cdc = 0.f, mc = 0.f;
            int hr = h - rs;   // wave-uniform
#pragma unroll
            for (int rr = 0; rr < 7; ++rr) {
                float c0 = cdb[(rs + rr) * NW + wc];
                float m0 = msb[(rs + rr) * NW + wc];
                if (rr == hr) { cdc = c0; mc = m0; }
                float cp1 = dpp_p1(c0), cp2 = dpp_p1(cp1), cp3 = dpp_p1(cp2);
                float cm1 = dpp_m1(c0), cm2 = dpp_m1(cm1), cm3 = dpp_m1(cm2);
                float mp1 = dpp_p1(m0), mp2 = dpp_p1(mp1), mp3 = dpp_p1(mp2);
                float mm1 = dpp_m1(m0), mm2 = dpp_m1(mm1), mm3 = dpp_m1(mm2);
                oc = fmaf(at[rr*7+0], cm3, oc); om = fmaf(at[rr*7+0], mm3, om);
                oc = fmaf(at[rr*7+1], cm2, oc); om = fmaf(at[rr*7+1], mm2, om);
                oc = fmaf(at[rr*7+2], cm1, oc); om = fmaf(at[rr*7+2], mm1, om);
                oc = fmaf(at[rr*7+3], c0 , oc); om = fmaf(at[rr*7+3], m0 , om);
                oc = fmaf(at[rr*7+4], cp1, oc); om = fmaf(at[rr*7+4], mp1, om);
                oc = fmaf(at[rr*7+5], cp2, oc); om = fmaf(at[rr*7+5], mp2, om);
                oc = fmaf(at[rr*7+6], cp3, oc); om = fmaf(at[rr*7+6], mp3, om);
            }
            oc *= inv; om *= inv;

            float sdc = sd[(size_t)b * NHW + h * NW + wc];
            float co = oc * mc + cdc * (1.f - mc);
            float mo = om;
            if (sdc > 0.f) { co = sdc; mo = mc; }
            if (act && wp >= 3 && wp <= 188) {
                int pidx = b * NHW + h * NW + wp;
                out_cd[pidx] = co;
                out_mask[pidx] = mo;
            }
        }
    } else {
        // ------------------ edge-column path ------------------
        int id = (blk - 768) * 4 + wv;     // 0..383
        int b  = id / 192;
        int h  = id % 192;
        int rs = min(max(h - 3, 0), NH - NK);
        int pr = 6 - (h - rs);
        int l  = lane;
        int i  = l / 7, j = l % 7;
        int ic = min(i, 6);
        bool al = (l < 49);

        const float* kb = kbuf + (size_t)b * NC * NHW;
        const float* qb = qbuf + (size_t)b * NC * NHW + h * NW;
        int offL = (rs + ic) * NW + j;          // left window: cs = 0
        int offR = (rs + ic) * NW + 185 + j;    // right window: cs = 185

        float aL0 = 0.f, aL1 = 0.f, aL2 = 0.f;
        float aR0 = 0.f, aR1 = 0.f, aR2 = 0.f;
        for (int c = 0; c < NC; ++c) {
            const float* kc = kb + (size_t)c * NHW;
            const float* qc = qb + (size_t)c * NHW;
            float kl = kc[offL], kr = kc[offR];
            float ql0 = qc[0],   ql1 = qc[1],   ql2 = qc[2];
            float qr0 = qc[189], qr1 = qc[190], qr2 = qc[191];
            aL0 = fmaf(ql0, kl, aL0); aL1 = fmaf(ql1, kl, aL1);
            aL2 = fmaf(ql2, kl, aL2);
            aR0 = fmaf(qr0, kr, aR0); aR1 = fmaf(qr1, kr, aR1);
            aR2 = fmaf(qr2, kr, aR2);
        }
        // bias: pc = 6,5,4 (left px 0,1,2), pc = 2,1,0 (right px 189,190,191)
        const float* rp = rpb + (pr + ic) * 13 + j;
        aL0 += rp[6]; aL1 += rp[5]; aL2 += rp[4];
        aR0 += rp[2]; aR1 += rp[1]; aR2 += rp[0];

        float e0, e1, e2, e3, e4, e5, s0, s1, s2, s3, s4, s5;
        {
            float v;
            v = al ? aL0 : -1e30f; v = wred_max(v);
            e0 = al ? __expf(aL0 - v) : 0.f; s0 = wred_sum(e0);
            v = al ? aL1 : -1e30f; v = wred_max(v);
            e1 = al ? __expf(aL1 - v) : 0.f; s1 = wred_sum(e1);
            v = al ? aL2 : -1e30f; v = wred_max(v);
            e2 = al ? __expf(aL2 - v) : 0.f; s2 = wred_sum(e2);
            v = al ? aR0 : -1e30f; v = wred_max(v);
            e3 = al ? __expf(aR0 - v) : 0.f; s3 = wred_sum(e3);
            v = al ? aR1 : -1e30f; v = wred_max(v);
            e4 = al ? __expf(aR1 - v) : 0.f; s4 = wred_sum(e4);
            v = al ? aR2 : -1e30f; v = wred_max(v);
            e5 = al ? __expf(aR2 - v) : 0.f; s5 = wred_sum(e5);
        }

        const float* cdb = cd   + (size_t)b * NHW;
        const float* msb = mask + (size_t)b * NHW;
        float cdL = cdb[offL], mL = msb[offL];
        float cdR = cdb[offR], mR = msb[offR];

        float oc0 = wred_sum(e0 * cdL), om0 = wred_sum(e0 * mL);
        float oc1 = wred_sum(e1 * cdL), om1 = wred_sum(e1 * mL);
        float oc2 = wred_sum(e2 * cdL), om2 = wred_sum(e2 * mL);
        float oc3 = wred_sum(e3 * cdR), om3 = wred_sum(e3 * mR);
        float oc4 = wred_sum(e4 * cdR), om4 = wred_sum(e4 * mR);
        float oc5 = wred_sum(e5 * cdR), om5 = wred_sum(e5 * mR);

        if (lane < 6) {
            int wpx = (lane < 3) ? lane : (186 + lane);
            float ocv = lane==0?oc0 : lane==1?oc1 : lane==2?oc2
                      : lane==3?oc3 : lane==4?oc4 : oc5;
            float omv = lane==0?om0 : lane==1?om1 : lane==2?om2
                      : lane==3?om3 : lane==4?om4 : om5;
            float smv = lane==0?s0  : lane==1?s1  : lane==2?s2
                      : lane==3?s3  : lane==4?s4  : s5;
            float inv = 1.f / smv;
            float oc = ocv * inv, om = omv * inv;
            int pidx = b * NHW + h * NW + wpx;
            float cdc = cdb[h * NW + wpx];
            float mc  = msb[h * NW + wpx];
            float sdc = sd[pidx];
            float co = oc * mc + cdc * (1.f - mc);
            float mo = om;
            if (sdc > 0.f) { co = sdc; mo = mc; }
            out_cd[pidx] = co;
            out_mask[pidx] = mo;
        }
    }
}

extern "C" void kernel_launch(void* const* d_in, const int* in_sizes, int n_in,
                              void* d_out, int out_size, void* d_ws, size_t ws_size,
                              hipStream_t stream) {
    const float* g      = (const float*)d_in[0];
    const float* cd     = (const float*)d_in[1];
    const float* sd     = (const float*)d_in[2];
    const float* mask   = (const float*)d_in[3];
    const float* ln_w   = (const float*)d_in[4];
    const float* ln_b   = (const float*)d_in[5];
    const float* conv_w = (const float*)d_in[6];
    const float* conv_b = (const float*)d_in[7];
    const float* rpb    = (const float*)d_in[8];

    float* out  = (float*)d_out;                 // [cd_out | mask_out]
    float* qbuf = (float*)d_ws;                  // NB*NC*NHW floats
    float* kbuf = qbuf + (size_t)NB * NC * NHW;  // NB*NC*NHW floats

    qk_reg<<<dim3(NPIX / 64), dim3(256), 0, stream>>>(
        g, cd, mask, ln_w, ln_b, conv_w, conv_b, qbuf, kbuf);
    attn_fused<<<dim3(768 + 96), dim3(256), 0, stream>>>(
        qbuf, kbuf, cd, sd, mask, rpb, out, out + NPIX);
}

// Round 9
// 154.044 us; speedup vs baseline: 2.1920x; 1.0570x over previous
//
#include <hip/hip_runtime.h>

constexpr int NB = 2;
constexpr int NC = 64;
constexpr int NH = 192;
constexpr int NW = 192;
constexpr int NK = 7;
constexpr int NHW = NH * NW;          // 36864
constexpr int NPIX = NB * NHW;        // 73728
constexpr float EPS = 1e-6f;

// ---------------------------------------------------------------------------
// Kernel 1 (v9): layernorm + 1x1 conv, pure-register formulation.
// 4 output rows per iteration (8 iterations of 260 s_load dwords + 260 FMAs):
// amortizes the SGPR-chunked s_load latency over 2x the FMAs vs v8.
// Plain __launch_bounds__(256) -- (256,4) caused a 64-VGPR spill storm (R7).
// ---------------------------------------------------------------------------
__global__ __launch_bounds__(256) void qk_reg(
    const float* __restrict__ g, const float* __restrict__ cd,
    const float* __restrict__ mask,
    const float* __restrict__ ln_w, const float* __restrict__ ln_b,
    const float* __restrict__ conv_w, const float* __restrict__ conv_b,
    float* __restrict__ qbuf, float* __restrict__ kbuf)
{
    int tid  = threadIdx.x;
    int lane = tid & 63;
    int wv   = __builtin_amdgcn_readfirstlane(tid >> 6);
    int kind = wv >> 1;                 // 0 -> q rows, 1 -> k rows
    int half = wv & 1;                  // lo/hi 32 outputs

    int b  = blockIdx.x / (NHW / 64);   // 576 blocks per batch
    int hw = (blockIdx.x - b * (NHW / 64)) * 64 + lane;
    int p  = b * NHW + hw;

    const float* gp = g + (size_t)b * NC * NHW + hw;

    float z[NC];
    float s0 = 0.f, s1 = 0.f, t0 = 0.f, t1 = 0.f;
#pragma unroll
    for (int c = 0; c < NC; c += 2) {
        float v0 = gp[(size_t)c * NHW];
        float v1 = gp[(size_t)(c + 1) * NHW];
        z[c] = v0; z[c + 1] = v1;
        s0 += v0; s1 += v1;
        t0 = fmaf(v0, v0, t0); t1 = fmaf(v1, v1, t1);
    }
    float mu   = (s0 + s1) * (1.f / NC);
    float var  = (t0 + t1) * (1.f / NC) - mu * mu;
    float rstd = rsqrtf(var + EPS);
#pragma unroll
    for (int c = 0; c < NC; c += 4) {
        float4 lw = *(const float4*)&ln_w[c];
        float4 lb = *(const float4*)&ln_b[c];
        z[c]     = fmaf((z[c]     - mu) * rstd, lw.x, lb.x);
        z[c + 1] = fmaf((z[c + 1] - mu) * rstd, lw.y, lb.y);
        z[c + 2] = fmaf((z[c + 2] - mu) * rstd, lw.z, lb.z);
        z[c + 3] = fmaf((z[c + 3] - mu) * rstd, lw.w, lb.w);
    }
    float zcd  = cd[p];
    float mval = mask[p];

    int orow = kind * 64 + half * 32;   // conv_w row base (wave-uniform)
    float* outb = (kind ? kbuf : qbuf) + ((size_t)b * NC + half * 32) * NHW + hw;

    for (int oo = 0; oo < 32; oo += 4) {
        const float* wr0 = conv_w + (size_t)(orow + oo) * 65;  // uniform
        const float* wr1 = wr0 + 65;
        const float* wr2 = wr0 + 130;
        const float* wr3 = wr0 + 195;
        float a0 = conv_b[orow + oo];
        float a1 = conv_b[orow + oo + 1];
        float a2 = conv_b[orow + oo + 2];
        float a3 = conv_b[orow + oo + 3];
#pragma unroll
        for (int c = 0; c < NC; ++c) {
            float zc = z[c];
            a0 = fmaf(wr0[c], zc, a0);
            a1 = fmaf(wr1[c], zc, a1);
            a2 = fmaf(wr2[c], zc, a2);
            a3 = fmaf(wr3[c], zc, a3);
        }
        a0 = fmaf(wr0[NC], zcd, a0);
        a1 = fmaf(wr1[NC], zcd, a1);
        a2 = fmaf(wr2[NC], zcd, a2);
        a3 = fmaf(wr3[NC], zcd, a3);
        if (kind) { a0 *= mval; a1 *= mval; a2 *= mval; a3 *= mval; }
        outb[(size_t)oo * NHW]       = a0;
        outb[(size_t)(oo + 1) * NHW] = a1;
        outb[(size_t)(oo + 2) * NHW] = a2;
        outb[(size_t)(oo + 3) * NHW] = a3;
    }
}

// ---------------------------------------------------------------------------
// Kernel 2 (v8, UNCHANGED for attribution): DPP attention, channel-split x2,
// edge columns in extra blocks.
// DPP facts (verified R6): 0x130 => lane i <- i+1; 0x138 => lane i <- i-1.
// ---------------------------------------------------------------------------
__device__ inline float dpp_p1(float x) {
    return __int_as_float(__builtin_amdgcn_mov_dpp(
        __float_as_int(x), 0x130, 0xf, 0xf, true));
}
__device__ inline float dpp_m1(float x) {
    return __int_as_float(__builtin_amdgcn_mov_dpp(
        __float_as_int(x), 0x138, 0xf, 0xf, true));
}
__device__ inline float wred_max(float v) {
#pragma unroll
    for (int m = 1; m < 64; m <<= 1) v = fmaxf(v, __shfl_xor(v, m));
    return v;
}
__device__ inline float wred_sum(float v) {
#pragma unroll
    for (int m = 1; m < 64; m <<= 1) v += __shfl_xor(v, m);
    return v;
}

__global__ __launch_bounds__(256) void attn_fused(
    const float* __restrict__ qbuf, const float* __restrict__ kbuf,
    const float* __restrict__ cd, const float* __restrict__ sd,
    const float* __restrict__ mask, const float* __restrict__ rpb,
    float* __restrict__ out_cd, float* __restrict__ out_mask)
{
    __shared__ float xch[2][48][49];    // 18.8 KB logit exchange

    int tid  = threadIdx.x;
    int lane = tid & 63;
    int wv   = __builtin_amdgcn_readfirstlane(tid >> 6);
    int blk  = blockIdx.x;

    if (blk < 768) {
        // ------------------ interior path ------------------
        int b   = blk / 384;
        int r   = blk % 384;
        int s   = r / 96;
        int h0  = (r % 96) * 2;
        int pair = wv >> 1;
        int chh  = wv & 1;
        int h  = h0 + pair;
        int wp = s * 48 + lane - 8;
        int wc = min(max(wp, 0), NW - 1);
        int rs = min(max(h - 3, 0), NH - NK);

        const float* kb = kbuf + (size_t)(b * NC + chh * 32) * NHW + rs * NW + wc;
        const float* qb = qbuf + (size_t)(b * NC + chh * 32) * NHW + h * NW + wc;

        float at[49];
#pragma unroll
        for (int n = 0; n < 49; ++n) at[n] = 0.f;

        float kvA[7], kvB[7];
        auto loadrow = [&](float (&dst)[7], int c) {
            const float* pp = kb + (size_t)c * NHW;
#pragma unroll
            for (int rr = 0; rr < 7; ++rr) dst[rr] = pp[rr * NW];
        };
        auto compute = [&](float (&cur)[7], float qc) {
#pragma unroll
            for (int rr = 0; rr < 7; ++rr) {
                float c0 = cur[rr];
                float p1 = dpp_p1(c0), p2 = dpp_p1(p1), p3 = dpp_p1(p2);
                float m1 = dpp_m1(c0), m2 = dpp_m1(m1), m3 = dpp_m1(m2);
                at[rr*7+0] = fmaf(qc, m3, at[rr*7+0]);
                at[rr*7+1] = fmaf(qc, m2, at[rr*7+1]);
                at[rr*7+2] = fmaf(qc, m1, at[rr*7+2]);
                at[rr*7+3] = fmaf(qc, c0, at[rr*7+3]);
                at[rr*7+4] = fmaf(qc, p1, at[rr*7+4]);
                at[rr*7+5] = fmaf(qc, p2, at[rr*7+5]);
                at[rr*7+6] = fmaf(qc, p3, at[rr*7+6]);
            }
        };

        float q0 = qb[0], q1 = qb[(size_t)1 * NHW];
        loadrow(kvA, 0);
        for (int c = 0; c < 32; c += 2) {
            if (c + 1 < 32) loadrow(kvB, c + 1);
            compute(kvA, q0);
            if (c + 2 < 32) { q0 = qb[(size_t)(c + 2) * NHW]; loadrow(kvA, c + 2); }
            if (c + 1 < 32) compute(kvB, q1);
            if (c + 3 < 32) q1 = qb[(size_t)(c + 3) * NHW];
        }

        bool act = (lane >= 8 && lane < 56);
        int px = lane - 8;
        if (chh == 1 && act) {
#pragma unroll
            for (int n = 0; n < 49; ++n) xch[pair][px][n] = at[n];
        }
        __syncthreads();
        if (chh == 0) {
            if (act) {
#pragma unroll
                for (int n = 0; n < 49; ++n) at[n] += xch[pair][px][n];
            }
            // bias (stored px all have pc == 3; pr wave-uniform)
            int pr = 6 - (h - rs);
            const float* rp = rpb + pr * 13 + 3;
#pragma unroll
            for (int i = 0; i < 7; ++i)
#pragma unroll
                for (int j = 0; j < 7; ++j)
                    at[i*7+j] += rp[i * 13 + j];

            float mx = -1e30f;
#pragma unroll
            for (int n = 0; n < 49; ++n) mx = fmaxf(mx, at[n]);
            float sm = 0.f;
#pragma unroll
            for (int n = 0; n < 49; ++n) { at[n] = __expf(at[n] - mx); sm += at[n]; }
            float inv = 1.f / sm;

            const float* cdb = cd   + (size_t)b * NHW;
            const float* msb = mask + (size_t)b * NHW;
            float oc = 0.f, om = 0.f, cdc = 0.f, mc = 0.f;
            int hr = h - rs;   // wave-uniform
#pragma unroll
            for (int rr = 0; rr < 7; ++rr) {
                float c0 = cdb[(rs + rr) * NW + wc];
                float m0 = msb[(rs + rr) * NW + wc];
                if (rr == hr) { cdc = c0; mc = m0; }
                float cp1 = dpp_p1(c0), cp2 = dpp_p1(cp1), cp3 = dpp_p1(cp2);
                float cm1 = dpp_m1(c0), cm2 = dpp_m1(cm1), cm3 = dpp_m1(cm2);
                float mp1 = dpp_p1(m0), mp2 = dpp_p1(mp1), mp3 = dpp_p1(mp2);
                float mm1 = dpp_m1(m0), mm2 = dpp_m1(mm1), mm3 = dpp_m1(mm2);
                oc = fmaf(at[rr*7+0], cm3, oc); om = fmaf(at[rr*7+0], mm3, om);
                oc = fmaf(at[rr*7+1], cm2, oc); om = fmaf(at[rr*7+1], mm2, om);
                oc = fmaf(at[rr*7+2], cm1, oc); om = fmaf(at[rr*7+2], mm1, om);
                oc = fmaf(at[rr*7+3], c0 , oc); om = fmaf(at[rr*7+3], m0 , om);
                oc = fmaf(at[rr*7+4], cp1, oc); om = fmaf(at[rr*7+4], mp1, om);
                oc = fmaf(at[rr*7+5], cp2, oc); om = fmaf(at[rr*7+5], mp2, om);
                oc = fmaf(at[rr*7+6], cp3, oc); om = fmaf(at[rr*7+6], mp3, om);
            }
            oc *= inv; om *= inv;

            float sdc = sd[(size_t)b * NHW + h * NW + wc];
            float co = oc * mc + cdc * (1.f - mc);
            float mo = om;
            if (sdc > 0.f) { co = sdc; mo = mc; }
            if (act && wp >= 3 && wp <= 188) {
                int pidx = b * NHW + h * NW + wp;
                out_cd[pidx] = co;
                out_mask[pidx] = mo;
            }
        }
    } else {
        // ------------------ edge-column path ------------------
        int id = (blk - 768) * 4 + wv;     // 0..383
        int b  = id / 192;
        int h  = id % 192;
        int rs = min(max(h - 3, 0), NH - NK);
        int pr = 6 - (h - rs);
        int l  = lane;
        int i  = l / 7, j = l % 7;
        int ic = min(i, 6);
        bool al = (l < 49);

        const float* kb = kbuf + (size_t)b * NC * NHW;
        const float* qb = qbuf + (size_t)b * NC * NHW + h * NW;
        int offL = (rs + ic) * NW + j;          // left window: cs = 0
        int offR = (rs + ic) * NW + 185 + j;    // right window: cs = 185

        float aL0 = 0.f, aL1 = 0.f, aL2 = 0.f;
        float aR0 = 0.f, aR1 = 0.f, aR2 = 0.f;
        for (int c = 0; c < NC; ++c) {
            const float* kc = kb + (size_t)c * NHW;
            const float* qc = qb + (size_t)c * NHW;
            float kl = kc[offL], kr = kc[offR];
            float ql0 = qc[0],   ql1 = qc[1],   ql2 = qc[2];
            float qr0 = qc[189], qr1 = qc[190], qr2 = qc[191];
            aL0 = fmaf(ql0, kl, aL0); aL1 = fmaf(ql1, kl, aL1);
            aL2 = fmaf(ql2, kl, aL2);
            aR0 = fmaf(qr0, kr, aR0); aR1 = fmaf(qr1, kr, aR1);
            aR2 = fmaf(qr2, kr, aR2);
        }
        // bias: pc = 6,5,4 (left px 0,1,2), pc = 2,1,0 (right px 189,190,191)
        const float* rp = rpb + (pr + ic) * 13 + j;
        aL0 += rp[6]; aL1 += rp[5]; aL2 += rp[4];
        aR0 += rp[2]; aR1 += rp[1]; aR2 += rp[0];

        float e0, e1, e2, e3, e4, e5, s0, s1, s2, s3, s4, s5;
        {
            float v;
            v = al ? aL0 : -1e30f; v = wred_max(v);
            e0 = al ? __expf(aL0 - v) : 0.f; s0 = wred_sum(e0);
            v = al ? aL1 : -1e30f; v = wred_max(v);
            e1 = al ? __expf(aL1 - v) : 0.f; s1 = wred_sum(e1);
            v = al ? aL2 : -1e30f; v = wred_max(v);
            e2 = al ? __expf(aL2 - v) : 0.f; s2 = wred_sum(e2);
            v = al ? aR0 : -1e30f; v = wred_max(v);
            e3 = al ? __expf(aR0 - v) : 0.f; s3 = wred_sum(e3);
            v = al ? aR1 : -1e30f; v = wred_max(v);
            e4 = al ? __expf(aR1 - v) : 0.f; s4 = wred_sum(e4);
            v = al ? aR2 : -1e30f; v = wred_max(v);
            e5 = al ? __expf(aR2 - v) : 0.f; s5 = wred_sum(e5);
        }

        const float* cdb = cd   + (size_t)b * NHW;
        const float* msb = mask + (size_t)b * NHW;
        float cdL = cdb[offL], mL = msb[offL];
        float cdR = cdb[offR], mR = msb[offR];

        float oc0 = wred_sum(e0 * cdL), om0 = wred_sum(e0 * mL);
        float oc1 = wred_sum(e1 * cdL), om1 = wred_sum(e1 * mL);
        float oc2 = wred_sum(e2 * cdL), om2 = wred_sum(e2 * mL);
        float oc3 = wred_sum(e3 * cdR), om3 = wred_sum(e3 * mR);
        float oc4 = wred_sum(e4 * cdR), om4 = wred_sum(e4 * mR);
        float oc5 = wred_sum(e5 * cdR), om5 = wred_sum(e5 * mR);

        if (lane < 6) {
            int wpx = (lane < 3) ? lane : (186 + lane);
            float ocv = lane==0?oc0 : lane==1?oc1 : lane==2?oc2
                      : lane==3?oc3 : lane==4?oc4 : oc5;
            float omv = lane==0?om0 : lane==1?om1 : lane==2?om2
                      : lane==3?om3 : lane==4?om4 : om5;
            float smv = lane==0?s0  : lane==1?s1  : lane==2?s2
                      : lane==3?s3  : lane==4?s4  : s5;
            float inv = 1.f / smv;
            float oc = ocv * inv, om = omv * inv;
            int pidx = b * NHW + h * NW + wpx;
            float cdc = cdb[h * NW + wpx];
            float mc  = msb[h * NW + wpx];
            float sdc = sd[pidx];
            float co = oc * mc + cdc * (1.f - mc);
            float mo = om;
            if (sdc > 0.f) { co = sdc; mo = mc; }
            out_cd[pidx] = co;
            out_mask[pidx] = mo;
        }
    }
}

extern "C" void kernel_launch(void* const* d_in, const int* in_sizes, int n_in,
                              void* d_out, int out_size, void* d_ws, size_t ws_size,
                              hipStream_t stream) {
    const float* g      = (const float*)d_in[0];
    const float* cd     = (const float*)d_in[1];
    const float* sd     = (const float*)d_in[2];
    const float* mask   = (const float*)d_in[3];
    const float* ln_w   = (const float*)d_in[4];
    const float* ln_b   = (const float*)d_in[5];
    const float* conv_w = (const float*)d_in[6];
    const float* conv_b = (const float*)d_in[7];
    const float* rpb    = (const float*)d_in[8];

    float* out  = (float*)d_out;                 // [cd_out | mask_out]
    float* qbuf = (float*)d_ws;                  // NB*NC*NHW floats
    float* kbuf = qbuf + (size_t)NB * NC * NHW;  // NB*NC*NHW floats

    qk_reg<<<dim3(NPIX / 64), dim3(256), 0, stream>>>(
        g, cd, mask, ln_w, ln_b, conv_w, conv_b, qbuf, kbuf);
    attn_fused<<<dim3(768 + 96), dim3(256), 0, stream>>>(
        qbuf, kbuf, cd, sd, mask, rpb, out, out + NPIX);
}